// Round 1
// baseline (30.943 us; speedup 1.0000x reference)
//
#include <hip/hip_runtime.h>
#include <hip/hip_bf16.h>
#include <math.h>

// Problem constants (fixed by setup_inputs): B=128, E=512, L=128, D=128, K=5
#define B_ 128
#define E_ 512
#define L_ 128
#define D_ 128
#define K_ 5
#define N_ (B_ * E_)          // 65536 rows
#define ROWOUT (B_ * K_)      // 640 output rows
#define OUT_TENSOR_SZ (ROWOUT * L_)  // 81920

// ---------------- Kernel 1: per-row cosine similarity ----------------
// One wave (64 lanes) per row; each lane loads a float2 from each vector.
__global__ __launch_bounds__(256) void cos_kernel(const float* __restrict__ a,
                                                  const float* __restrict__ b,
                                                  float* __restrict__ cosout) {
    const int row  = blockIdx.x * 4 + (threadIdx.x >> 6);
    const int lane = threadIdx.x & 63;
    const float2* a2 = reinterpret_cast<const float2*>(a) + (size_t)row * (D_ / 2) + lane;
    const float2* b2 = reinterpret_cast<const float2*>(b) + (size_t)row * (D_ / 2) + lane;
    float2 av = *a2;
    float2 bv = *b2;
    float dot = av.x * bv.x + av.y * bv.y;
    float na  = av.x * av.x + av.y * av.y;
    float nb  = bv.x * bv.x + bv.y * bv.y;
    #pragma unroll
    for (int o = 32; o; o >>= 1) {
        dot += __shfl_xor(dot, o);
        na  += __shfl_xor(na,  o);
        nb  += __shfl_xor(nb,  o);
    }
    if (lane == 0) {
        const float eps = 1e-8f;
        float denom = fmaxf(sqrtf(na), eps) * fmaxf(sqrtf(nb), eps);
        cosout[row] = dot / denom;
    }
}

// ---------------- Kernel 2: softmax over E + top-5 (value desc, index asc) ----
__global__ __launch_bounds__(512) void softmax_topk_kernel(const float* __restrict__ cosv,
                                                           float* __restrict__ out_topcos,
                                                           int* __restrict__ top_idx) {
    const int b    = blockIdx.x;
    const int e    = threadIdx.x;          // 0..511
    const int wid  = e >> 6;
    const int lane = e & 63;

    __shared__ float red[8];
    __shared__ float ps[E_];
    __shared__ float wval[8];
    __shared__ int   widx[8];
    __shared__ int   bwin_i;

    float v = cosv[b * E_ + e];

    // block max
    float m = v;
    #pragma unroll
    for (int o = 32; o; o >>= 1) m = fmaxf(m, __shfl_xor(m, o));
    if (lane == 0) red[wid] = m;
    __syncthreads();
    float mall = red[0];
    #pragma unroll
    for (int i = 1; i < 8; i++) mall = fmaxf(mall, red[i]);
    __syncthreads();

    // block sum of exp
    float ex = expf(v - mall);
    float s = ex;
    #pragma unroll
    for (int o = 32; o; o >>= 1) s += __shfl_xor(s, o);
    if (lane == 0) red[wid] = s;
    __syncthreads();
    float sall = 0.f;
    #pragma unroll
    for (int i = 0; i < 8; i++) sall += red[i];

    float p = ex / sall;
    ps[e] = p;
    __syncthreads();

    // 5 rounds of block argmax with tie-break: larger value wins; equal value -> smaller index
    for (int k = 0; k < K_; k++) {
        float val = ps[e];
        int   idx = e;
        #pragma unroll
        for (int o = 32; o; o >>= 1) {
            float ov = __shfl_xor(val, o);
            int   oi = __shfl_xor(idx, o);
            if (ov > val || (ov == val && oi < idx)) { val = ov; idx = oi; }
        }
        if (lane == 0) { wval[wid] = val; widx[wid] = idx; }
        __syncthreads();
        if (e == 0) {
            float bv = wval[0]; int bi = widx[0];
            #pragma unroll
            for (int i = 1; i < 8; i++) {
                if (wval[i] > bv || (wval[i] == bv && widx[i] < bi)) { bv = wval[i]; bi = widx[i]; }
            }
            bwin_i = bi;
            out_topcos[b * K_ + k] = bv;
            top_idx[b * K_ + k]    = bi;
        }
        __syncthreads();
        if (e == bwin_i) ps[e] = -INFINITY;
        __syncthreads();
    }
}

// ---------------- Kernel 3: gather selected rows, write as f32 ----------------
// One block (128 threads) per output row r = b*K + k.
__global__ __launch_bounds__(128) void gather_kernel(const int* __restrict__ ids_c,
                                                     const int* __restrict__ ids_e,
                                                     const int* __restrict__ m_c,
                                                     const int* __restrict__ m_e,
                                                     const int* __restrict__ t_c,
                                                     const int* __restrict__ t_e,
                                                     const int* __restrict__ top_idx,
                                                     float* __restrict__ out) {
    const int r = blockIdx.x;            // 0..639
    const int b = r / K_;
    const int k = r - b * K_;
    const size_t crow = (size_t)(b * E_ + k) * L_;
    const size_t erow = (size_t)(b * E_ + top_idx[r]) * L_;
    const int j = threadIdx.x;           // 0..127
    float* o1 = out + 640 + (size_t)0 * OUT_TENSOR_SZ + (size_t)r * L_;
    float* o2 = out + 640 + (size_t)1 * OUT_TENSOR_SZ + (size_t)r * L_;
    float* o3 = out + 640 + (size_t)2 * OUT_TENSOR_SZ + (size_t)r * L_;
    float* o4 = out + 640 + (size_t)3 * OUT_TENSOR_SZ + (size_t)r * L_;
    float* o5 = out + 640 + (size_t)4 * OUT_TENSOR_SZ + (size_t)r * L_;
    float* o6 = out + 640 + (size_t)5 * OUT_TENSOR_SZ + (size_t)r * L_;
    o1[j] = (float)ids_c[crow + j];
    o2[j] = (float)ids_e[erow + j];
    o3[j] = (float)m_c[crow + j];
    o4[j] = (float)m_e[erow + j];
    o5[j] = (float)t_c[crow + j];
    o6[j] = (float)t_e[erow + j];
}

extern "C" void kernel_launch(void* const* d_in, const int* in_sizes, int n_in,
                              void* d_out, int out_size, void* d_ws, size_t ws_size,
                              hipStream_t stream) {
    const float* claim_vec    = (const float*)d_in[0];
    const float* evidence_vec = (const float*)d_in[1];
    const int*   ids_claim    = (const int*)d_in[2];
    const int*   ids_evidence = (const int*)d_in[3];
    const int*   masks_claim  = (const int*)d_in[4];
    const int*   masks_evid   = (const int*)d_in[5];
    const int*   token_claim  = (const int*)d_in[6];
    const int*   token_evid   = (const int*)d_in[7];

    float* cos_ws  = (float*)d_ws;                              // N_ floats
    int*   idx_ws  = (int*)((char*)d_ws + (size_t)N_ * sizeof(float)); // 640 ints
    float* out     = (float*)d_out;

    // 1) cosine per row: 4 rows per 256-thread block
    cos_kernel<<<N_ / 4, 256, 0, stream>>>(claim_vec, evidence_vec, cos_ws);
    // 2) softmax + top-5 per batch row
    softmax_topk_kernel<<<B_, 512, 0, stream>>>(cos_ws, out, idx_ws);
    // 3) gather/copy selected rows
    gather_kernel<<<ROWOUT, 128, 0, stream>>>(ids_claim, ids_evidence,
                                              masks_claim, masks_evid,
                                              token_claim, token_evid,
                                              idx_ws, out);
}

// Round 2
// 22.765 us; speedup vs baseline: 1.3592x; 1.3592x over previous
//
#include <hip/hip_runtime.h>
#include <hip/hip_bf16.h>
#include <math.h>

// Problem constants (fixed by setup_inputs): B=128, E=512, L=128, D=128, K=5
#define B_ 128
#define E_ 512
#define L_ 128
#define D_ 128
#define K_ 5
#define N_ (B_ * E_)                 // 65536 rows
#define ROWOUT (B_ * K_)             // 640 output rows
#define OUT_TENSOR_SZ (ROWOUT * L_)  // 81920

// ---------------- Kernel 1: per-row cosine similarity ----------------
// float4 loads: 32 lanes per row, 2 rows per wave, 8 rows per 256-thr block.
__global__ __launch_bounds__(256) void cos_kernel(const float* __restrict__ a,
                                                  const float* __restrict__ b,
                                                  float* __restrict__ cosout) {
    const int row  = blockIdx.x * 8 + (threadIdx.x >> 5);
    const int l32  = threadIdx.x & 31;
    const float4* a4 = reinterpret_cast<const float4*>(a) + (size_t)row * (D_ / 4) + l32;
    const float4* b4 = reinterpret_cast<const float4*>(b) + (size_t)row * (D_ / 4) + l32;
    float4 av = *a4;
    float4 bv = *b4;
    float dot = av.x * bv.x + av.y * bv.y + av.z * bv.z + av.w * bv.w;
    float na  = av.x * av.x + av.y * av.y + av.z * av.z + av.w * av.w;
    float nb  = bv.x * bv.x + bv.y * bv.y + bv.z * bv.z + bv.w * bv.w;
    #pragma unroll
    for (int o = 16; o; o >>= 1) {           // stays within each 32-lane half
        dot += __shfl_xor(dot, o);
        na  += __shfl_xor(na,  o);
        nb  += __shfl_xor(nb,  o);
    }
    if (l32 == 0) {
        const float eps = 1e-8f;
        float denom = fmaxf(sqrtf(na), eps) * fmaxf(sqrtf(nb), eps);
        cosout[row] = dot / denom;
    }
}

// ------- Kernel 2 (fused): softmax over E + top-5 + gather of selected rows ----
__global__ __launch_bounds__(512) void softmax_topk_gather_kernel(
        const float* __restrict__ cosv,
        const int* __restrict__ ids_c, const int* __restrict__ ids_e,
        const int* __restrict__ m_c,   const int* __restrict__ m_e,
        const int* __restrict__ t_c,   const int* __restrict__ t_e,
        float* __restrict__ out) {
    const int b    = blockIdx.x;
    const int e    = threadIdx.x;          // 0..511
    const int wid  = e >> 6;
    const int lane = e & 63;

    __shared__ float red[8];
    __shared__ float ps[E_];
    __shared__ int   topidx[K_];

    float v = cosv[b * E_ + e];

    // block max
    float m = v;
    #pragma unroll
    for (int o = 32; o; o >>= 1) m = fmaxf(m, __shfl_xor(m, o));
    if (lane == 0) red[wid] = m;
    __syncthreads();
    float mall = red[0];
    #pragma unroll
    for (int i = 1; i < 8; i++) mall = fmaxf(mall, red[i]);
    __syncthreads();

    // block sum of exp
    float ex = expf(v - mall);
    float s = ex;
    #pragma unroll
    for (int o = 32; o; o >>= 1) s += __shfl_xor(s, o);
    if (lane == 0) red[wid] = s;
    __syncthreads();
    float sall = 0.f;
    #pragma unroll
    for (int i = 0; i < 8; i++) sall += red[i];

    ps[e] = ex / sall;
    __syncthreads();

    // ---- top-5 entirely within wave 0, registers only, no barriers ----
    if (wid == 0) {
        float vals[8];
        #pragma unroll
        for (int j = 0; j < 8; j++) vals[j] = ps[j * 64 + lane];

        for (int k = 0; k < K_; k++) {
            // local best over 8 regs (ascending index, strict > keeps smallest idx on tie)
            float val = vals[0];
            int   idx = lane;
            #pragma unroll
            for (int j = 1; j < 8; j++) {
                if (vals[j] > val) { val = vals[j]; idx = j * 64 + lane; }
            }
            // wave argmax: larger value wins; equal value -> smaller index
            #pragma unroll
            for (int o = 32; o; o >>= 1) {
                float ov = __shfl_xor(val, o);
                int   oi = __shfl_xor(idx, o);
                if (ov > val || (ov == val && oi < idx)) { val = ov; idx = oi; }
            }
            if (lane == 0) {
                out[b * K_ + k] = val;
                topidx[k] = idx;
            }
            // invalidate winner (compile-time reg index to avoid scratch)
            #pragma unroll
            for (int j = 0; j < 8; j++) {
                if ((idx >> 6) == j && (idx & 63) == lane) vals[j] = -INFINITY;
            }
        }
    }
    __syncthreads();

    // ---- gather: wave k copies output row r = b*K + k (k = 0..4) ----
    if (wid < K_) {
        const int k = wid;
        const int r = b * K_ + k;
        const size_t crow = (size_t)(b * E_ + k) * L_;
        const size_t erow = (size_t)(b * E_ + topidx[k]) * L_;
        const int q  = lane & 31;       // int4 index within a row (0..31)
        const int hi = lane >> 5;       // 0 -> claim-side tensor, 1 -> evidence-side
        // tensor pairs: (ids_c,ids_e), (m_c,m_e), (t_c,t_e)
        const int4* s0 = reinterpret_cast<const int4*>(hi ? (ids_e + erow) : (ids_c + crow));
        const int4* s1 = reinterpret_cast<const int4*>(hi ? (m_e   + erow) : (m_c   + crow));
        const int4* s2 = reinterpret_cast<const int4*>(hi ? (t_e   + erow) : (t_c   + crow));
        float4* d0 = reinterpret_cast<float4*>(out + 640 + (size_t)(0 + hi) * OUT_TENSOR_SZ + (size_t)r * L_);
        float4* d1 = reinterpret_cast<float4*>(out + 640 + (size_t)(2 + hi) * OUT_TENSOR_SZ + (size_t)r * L_);
        float4* d2 = reinterpret_cast<float4*>(out + 640 + (size_t)(4 + hi) * OUT_TENSOR_SZ + (size_t)r * L_);
        int4 v0 = s0[q];
        int4 v1 = s1[q];
        int4 v2 = s2[q];
        d0[q] = make_float4((float)v0.x, (float)v0.y, (float)v0.z, (float)v0.w);
        d1[q] = make_float4((float)v1.x, (float)v1.y, (float)v1.z, (float)v1.w);
        d2[q] = make_float4((float)v2.x, (float)v2.y, (float)v2.z, (float)v2.w);
    }
}

extern "C" void kernel_launch(void* const* d_in, const int* in_sizes, int n_in,
                              void* d_out, int out_size, void* d_ws, size_t ws_size,
                              hipStream_t stream) {
    const float* claim_vec    = (const float*)d_in[0];
    const float* evidence_vec = (const float*)d_in[1];
    const int*   ids_claim    = (const int*)d_in[2];
    const int*   ids_evidence = (const int*)d_in[3];
    const int*   masks_claim  = (const int*)d_in[4];
    const int*   masks_evid   = (const int*)d_in[5];
    const int*   token_claim  = (const int*)d_in[6];
    const int*   token_evid   = (const int*)d_in[7];

    float* cos_ws = (float*)d_ws;   // N_ floats
    float* out    = (float*)d_out;

    // 1) cosine per row: 8 rows per 256-thread block (float4 loads)
    cos_kernel<<<N_ / 8, 256, 0, stream>>>(claim_vec, evidence_vec, cos_ws);
    // 2) fused softmax + top-5 + gather
    softmax_topk_gather_kernel<<<B_, 512, 0, stream>>>(cos_ws,
                                                       ids_claim, ids_evidence,
                                                       masks_claim, masks_evid,
                                                       token_claim, token_evid,
                                                       out);
}